// Round 1
// baseline (4052.707 us; speedup 1.0000x reference)
//
#include <hip/hip_runtime.h>
#include <math.h>

#define B_    128
#define CIN   128
#define TIN   2500
#define COUT  64
#define KW    27
#define TOUT  625
#define TT    16   // t-tile

// ---------------------------------------------------------------------------
// K0: per-output-channel alpha = mean|w|, write binarized weights transposed:
//     wbinT[(c*27+k)*64 + o] = sign(w[o,c,k]) * alpha[o]
// ---------------------------------------------------------------------------
__global__ void binarize_kernel(const float* __restrict__ w, float* __restrict__ wbinT) {
    int o = blockIdx.x, tid = threadIdx.x;
    __shared__ float red[256];
    const float* wo_ = w + (size_t)o * (CIN * KW);
    float s = 0.f;
    for (int idx = tid; idx < CIN * KW; idx += 256) s += fabsf(wo_[idx]);
    red[tid] = s;
    __syncthreads();
    for (int st = 128; st > 0; st >>= 1) {
        if (tid < st) red[tid] += red[tid + st];
        __syncthreads();
    }
    float alpha = red[0] / (float)(CIN * KW);
    for (int idx = tid; idx < CIN * KW; idx += 256) {
        float v = wo_[idx];
        float q = v > 0.f ? alpha : (v < 0.f ? -alpha : 0.f);
        wbinT[(size_t)idx * 64 + o] = q;
    }
}

// ---------------------------------------------------------------------------
// K0b: transpose the four 64x64 projection matrices: dstT[c*64+o] = src[o*64+c]
// ---------------------------------------------------------------------------
__global__ void transpose_w_kernel(const float* __restrict__ wq, const float* __restrict__ wk,
                                   const float* __restrict__ wv, const float* __restrict__ wo,
                                   float* __restrict__ dstT) {
    const float* srcs[4] = {wq, wk, wv, wo};
    const float* src = srcs[blockIdx.x];
    float* dst = dstT + (size_t)blockIdx.x * 4096;
    for (int idx = threadIdx.x; idx < 4096; idx += 256) {
        int o = idx >> 6, c = idx & 63;
        dst[c * 64 + o] = src[idx];
    }
}

// ---------------------------------------------------------------------------
// K1: binarized conv1d (stride 4, pad 13) + bias + BN + ELU -> y
//     fused q,k,v projections (spike on the fly) -> qT,kT,vT in [b][t][c]
// Block: 256 thr = (o = tid&63, part = tid>>6), one (b, 16-t tile) per block.
// ---------------------------------------------------------------------------
__global__ __launch_bounds__(256, 2) void conv_kernel(
    const float* __restrict__ x, const float* __restrict__ wbinT,
    const float* __restrict__ bias, const float* __restrict__ gamma_, const float* __restrict__ beta_,
    const float* __restrict__ mean_, const float* __restrict__ var_,
    const float* __restrict__ wqT, const float* __restrict__ wkT, const float* __restrict__ wvT,
    float* __restrict__ y_out, float* __restrict__ qT, float* __restrict__ kT, float* __restrict__ vT)
{
    __shared__ float x_sh[CIN * 88];        // 45056 B (span 87, padded to 88)
    __shared__ float red_sh[4 * 64 * TT];   // 16384 B
    int b = blockIdx.y;
    int t0 = blockIdx.x * TT;
    int tid = threadIdx.x;

    // stage x window: local j in [0,87), global g = 4*t0-13+j, zero-padded
    const float* xb = x + (size_t)b * CIN * TIN;
    int base = 4 * t0 - 13;
    for (int idx = tid; idx < CIN * 88; idx += 256) {
        int c = idx / 88, j = idx - c * 88;
        int g = base + j;
        float v = 0.f;
        if (j < 87 && g >= 0 && g < TIN) v = xb[c * TIN + g];
        x_sh[idx] = v;
    }
    __syncthreads();

    int o = tid & 63, part = tid >> 6;
    float acc[TT];
#pragma unroll
    for (int i = 0; i < TT; i++) acc[i] = 0.f;

#pragma unroll 1
    for (int cc = 0; cc < 32; ++cc) {
        int c = part * 32 + cc;
        float wreg[KW];
#pragma unroll
        for (int k = 0; k < KW; k++) wreg[k] = wbinT[(c * KW + k) * 64 + o];
        const float* xr = &x_sh[c * 88];
        // j = 4*ti + k  =>  k ≡ j (mod 4), ti = (j>>2) - m for k = (j&3)+4m
#pragma unroll
        for (int j4 = 0; j4 < 88; j4 += 4) {
            float4 xv = *(const float4*)&xr[j4];
            float xs[4] = {xv.x, xv.y, xv.z, xv.w};
#pragma unroll
            for (int r = 0; r < 4; r++) {
#pragma unroll
                for (int m = 0; m < 7; m++) {
                    int k = r + 4 * m;
                    int ti = (j4 + r) / 4 - m;
                    if (k < KW && ti >= 0 && ti < TT)
                        acc[ti] += wreg[k] * xs[r];
                }
            }
        }
    }
#pragma unroll
    for (int i = 0; i < TT; i++) red_sh[(part * 64 + o) * TT + i] = acc[i];
    __syncthreads();

    // epilogue: reduce parts, bias + BN + ELU, write y, keep y tile in LDS
    float* y_sh = x_sh;  // reuse (needs 1024 floats)
    for (int cell = tid; cell < 64 * TT; cell += 256) {
        int oo = cell >> 4, ti = cell & 15;
        float s = red_sh[(0 * 64 + oo) * TT + ti] + red_sh[(1 * 64 + oo) * TT + ti]
                + red_sh[(2 * 64 + oo) * TT + ti] + red_sh[(3 * 64 + oo) * TT + ti];
        s += bias[oo];
        float inv = 1.f / sqrtf(var_[oo] + 1e-5f);
        s = (s - mean_[oo]) * (inv * gamma_[oo]) + beta_[oo];
        float yv = s > 0.f ? s : expm1f(s);
        int t = t0 + ti;
        if (t < TOUT) y_out[((size_t)b * COUT + oo) * TOUT + t] = yv;
        y_sh[cell] = yv;  // y_sh[oo*16 + ti]
    }
    __syncthreads();

    // fused projections: q = wq@spike(y), k = wk@spike(y), v = wv@y
    for (int cell = tid; cell < 64 * TT; cell += 256) {
        int oo = cell & 63, ti = cell >> 6;
        float sq = 0.f, sk = 0.f, sv = 0.f;
#pragma unroll
        for (int c = 0; c < 64; c++) {
            float yv = y_sh[c * TT + ti];
            float sp = yv > 0.f ? 1.f : 0.f;
            sq += wqT[c * 64 + oo] * sp;
            sk += wkT[c * 64 + oo] * sp;
            sv += wvT[c * 64 + oo] * yv;
        }
        int t = t0 + ti;
        if (t < TOUT) {
            size_t off = ((size_t)b * TOUT + t) * 64 + oo;
            qT[off] = sq; kT[off] = sk; vT[off] = sv;
        }
    }
}

// ---------------------------------------------------------------------------
// K2: attention per (b, 16-t tile): scores (exact, in LDS) -> softmax ->
//     ctx -> out = y + wo@ctx
// ---------------------------------------------------------------------------
__global__ __launch_bounds__(256, 2) void attn_kernel(
    const float* __restrict__ qT, const float* __restrict__ kT, const float* __restrict__ vT,
    const float* __restrict__ y, const float* __restrict__ woT, float* __restrict__ out)
{
    __shared__ float sc_sh[16 * 628];   // 40192 B, row stride 628 (16B aligned)
    __shared__ float kv_sh[64 * 68];    // 17408 B
    __shared__ float qc_sh[1088];       // q tile [ti*64+c]; later ctx [c*17+ti]
    __shared__ float red_sh[256];
    __shared__ float rden[16];

    int b = blockIdx.y, t0 = blockIdx.x * TT, tid = threadIdx.x;
    int nt = min(TT, TOUT - t0);

    // stage q (zero invalid rows -> guard-free compute, no NaNs)
    for (int idx = tid; idx < 16 * 64; idx += 256) {
        int ti = idx >> 6, c = idx & 63;
        qc_sh[ti * 64 + c] = (ti < nt) ? qT[((size_t)b * TOUT + t0 + ti) * 64 + c] : 0.f;
    }

    int ti1 = tid >> 4, sg = tid & 15;

    // ---- phase 1: scores[ti][s] = (q·k)/8 ----
    for (int s0 = 0; s0 < TOUT; s0 += 64) {
        int ns = min(64, TOUT - s0);
        __syncthreads();
        for (int idx = tid; idx < 64 * 64; idx += 256) {  // k c-major, stride 68
            int c = idx >> 6, si = idx & 63;
            kv_sh[c * 68 + si] = (si < ns) ? kT[((size_t)b * TOUT + s0 + si) * 64 + c] : 0.f;
        }
        __syncthreads();
        float a0 = 0, a1 = 0, a2 = 0, a3 = 0;
        const float* qrow = &qc_sh[ti1 * 64];
#pragma unroll
        for (int c = 0; c < 64; c++) {
            float qv = qrow[c];
            float4 k4 = *(const float4*)&kv_sh[c * 68 + sg * 4];
            a0 += qv * k4.x; a1 += qv * k4.y; a2 += qv * k4.z; a3 += qv * k4.w;
        }
        float4 r;
        r.x = a0 * 0.125f; r.y = a1 * 0.125f; r.z = a2 * 0.125f; r.w = a3 * 0.125f;
        *(float4*)&sc_sh[ti1 * 628 + s0 + sg * 4] = r;
    }
    __syncthreads();

    // ---- softmax over s (2-pass, denom folded into epilogue) ----
    float mx = -3.0e38f;
    for (int s = sg; s < TOUT; s += 16) mx = fmaxf(mx, sc_sh[ti1 * 628 + s]);
    red_sh[tid] = mx;
    __syncthreads();
    float rowm = red_sh[ti1 * 16];
#pragma unroll
    for (int l = 1; l < 16; l++) rowm = fmaxf(rowm, red_sh[ti1 * 16 + l]);
    __syncthreads();
    float sum = 0.f;
    for (int s = sg; s < TOUT; s += 16) {
        float e = __expf(sc_sh[ti1 * 628 + s] - rowm);
        sc_sh[ti1 * 628 + s] = e;
        sum += e;
    }
    red_sh[tid] = sum;
    __syncthreads();
    if (tid < 16) {
        float tot = 0.f;
#pragma unroll
        for (int l = 0; l < 16; l++) tot += red_sh[tid * 16 + l];
        rden[tid] = 1.f / tot;
    }

    // ---- phase 2: ctx[c][ti] = sum_s e[ti][s] * v[c][s] ----
    int cc = tid & 63, tg = tid >> 6;
    float ctx0 = 0, ctx1 = 0, ctx2 = 0, ctx3 = 0;  // rows ti = 4*tg + {0..3}
    for (int s0 = 0; s0 < TOUT; s0 += 64) {
        int ns = min(64, TOUT - s0);
        __syncthreads();
        for (int idx = tid; idx < 64 * 64; idx += 256) {  // v s-major, stride 64
            int si = idx >> 6, c = idx & 63;
            kv_sh[si * 64 + c] = (si < ns) ? vT[((size_t)b * TOUT + s0 + si) * 64 + c] : 0.f;
        }
        __syncthreads();
        const float* srow = &sc_sh[(tg * 4) * 628 + s0];
#pragma unroll 1
        for (int si = 0; si < 64; si++) {
            float vv = kv_sh[si * 64 + cc];
            ctx0 += srow[si] * vv;
            ctx1 += srow[628 + si] * vv;
            ctx2 += srow[1256 + si] * vv;
            ctx3 += srow[1884 + si] * vv;
        }
    }

    // ---- epilogue: normalize, transpose ctx through LDS, out = y + wo@ctx ----
    __syncthreads();
    float* ctx_sh = qc_sh;  // [c*17 + ti], max index 63*17+15 = 1086 < 1088
    ctx_sh[cc * 17 + tg * 4 + 0] = ctx0 * rden[tg * 4 + 0];
    ctx_sh[cc * 17 + tg * 4 + 1] = ctx1 * rden[tg * 4 + 1];
    ctx_sh[cc * 17 + tg * 4 + 2] = ctx2 * rden[tg * 4 + 2];
    ctx_sh[cc * 17 + tg * 4 + 3] = ctx3 * rden[tg * 4 + 3];
    __syncthreads();
    for (int cell = tid; cell < 64 * TT; cell += 256) {
        int oo = cell >> 4, ti = cell & 15;
        if (ti < nt) {
            float acc = 0.f;
#pragma unroll
            for (int c = 0; c < 64; c++) acc += woT[c * 64 + oo] * ctx_sh[c * 17 + ti];
            size_t off = ((size_t)b * COUT + oo) * TOUT + t0 + ti;
            out[off] = y[off] + acc;
        }
    }
}

// ---------------------------------------------------------------------------
extern "C" void kernel_launch(void* const* d_in, const int* in_sizes, int n_in,
                              void* d_out, int out_size, void* d_ws, size_t ws_size,
                              hipStream_t stream) {
    const float* x        = (const float*)d_in[0];
    const float* conv_w   = (const float*)d_in[1];
    const float* conv_b   = (const float*)d_in[2];
    const float* bn_gamma = (const float*)d_in[3];
    const float* bn_beta  = (const float*)d_in[4];
    const float* bn_mean  = (const float*)d_in[5];
    const float* bn_var   = (const float*)d_in[6];
    const float* wq       = (const float*)d_in[7];
    const float* wk       = (const float*)d_in[8];
    const float* wv       = (const float*)d_in[9];
    const float* wo       = (const float*)d_in[10];
    float* out = (float*)d_out;
    float* ws  = (float*)d_ws;

    // ws layout (floats)
    float* wbinT = ws;                    // 221184
    float* wT4   = ws + 221184;           // 4*4096 (wqT, wkT, wvT, woT)
    float* yb    = ws + 237568;           // 5120000  y[b][o][t]
    float* qTp   = ws + 5357568;          // 5120000  q[b][t][c]
    float* kTp   = ws + 10477568;         // 5120000
    float* vTp   = ws + 15597568;         // 5120000

    hipLaunchKernelGGL(binarize_kernel, dim3(64), dim3(256), 0, stream, conv_w, wbinT);
    hipLaunchKernelGGL(transpose_w_kernel, dim3(4), dim3(256), 0, stream, wq, wk, wv, wo, wT4);
    hipLaunchKernelGGL(conv_kernel, dim3(40, 128), dim3(256), 0, stream,
                       x, wbinT, conv_b, bn_gamma, bn_beta, bn_mean, bn_var,
                       wT4, wT4 + 4096, wT4 + 8192, yb, qTp, kTp, vTp);
    hipLaunchKernelGGL(attn_kernel, dim3(40, 128), dim3(256), 0, stream,
                       qTp, kTp, vTp, yb, wT4 + 12288, out);
}

// Round 3
// 3728.400 us; speedup vs baseline: 1.0870x; 1.0870x over previous
//
#include <hip/hip_runtime.h>
#include <math.h>

#define B_    128
#define CIN   128
#define TIN   2500
#define COUT  64
#define KW    27
#define TOUT  625
#define TT    16    // attn t-tile
#define CTT   32    // conv t-tile
#define GROWS 152   // conv staging rows (span 4*31+27=151, pad to 152)

typedef __bf16 bf16x8 __attribute__((ext_vector_type(8)));
typedef float  f32x4  __attribute__((ext_vector_type(4)));

__device__ __forceinline__ unsigned short f32_to_bf16_rne(float v) {
    unsigned u = __float_as_uint(v);
    u += 0x7FFFu + ((u >> 16) & 1u);
    return (unsigned short)(u >> 16);
}

// ---------------------------------------------------------------------------
// K0: alpha[o] = mean|w|; sign matrix as bf16 bits, layout wsgn[kk][o][c]
// ---------------------------------------------------------------------------
__global__ void binarize_kernel(const float* __restrict__ w,
                                unsigned short* __restrict__ wsgn,
                                float* __restrict__ alpha_out) {
    int o = blockIdx.x, tid = threadIdx.x;
    __shared__ float red[256];
    const float* wo_ = w + (size_t)o * (CIN * KW);
    float s = 0.f;
    for (int idx = tid; idx < CIN * KW; idx += 256) s += fabsf(wo_[idx]);
    red[tid] = s;
    __syncthreads();
    for (int st = 128; st > 0; st >>= 1) {
        if (tid < st) red[tid] += red[tid + st];
        __syncthreads();
    }
    if (tid == 0) alpha_out[o] = red[0] / (float)(CIN * KW);
    for (int idx = tid; idx < CIN * KW; idx += 256) {
        float v = wo_[idx];
        int c = idx / KW, kk = idx - c * KW;
        unsigned short bits = v > 0.f ? 0x3F80u : (v < 0.f ? 0xBF80u : 0u);
        wsgn[((size_t)kk * 64 + o) * 128 + c] = bits;
    }
}

// ---------------------------------------------------------------------------
// K0b: transpose 4 projection mats; block 4 folds alpha+bias+BN into scA/scB
// ---------------------------------------------------------------------------
__global__ void transpose_w_kernel(const float* __restrict__ wq, const float* __restrict__ wk,
                                   const float* __restrict__ wv, const float* __restrict__ wo,
                                   const float* __restrict__ conv_b, const float* __restrict__ gamma_,
                                   const float* __restrict__ beta_, const float* __restrict__ mean_,
                                   const float* __restrict__ var_, const float* __restrict__ alpha_,
                                   float* __restrict__ dstT, float* __restrict__ scA, float* __restrict__ scB) {
    if (blockIdx.x < 4) {
        const float* srcs[4] = {wq, wk, wv, wo};
        const float* src = srcs[blockIdx.x];
        float* dst = dstT + (size_t)blockIdx.x * 4096;
        for (int idx = threadIdx.x; idx < 4096; idx += 256) {
            int o = idx >> 6, c = idx & 63;
            dst[c * 64 + o] = src[idx];
        }
    } else {
        int o = threadIdx.x;
        if (o < 64) {
            float inv = rsqrtf(var_[o] + 1e-5f);
            float G = gamma_[o] * inv;
            scA[o] = alpha_[o] * G;
            scB[o] = (conv_b[o] - mean_[o]) * G + beta_[o];
        }
    }
}

// ---------------------------------------------------------------------------
// K1: binarized conv1d via bf16 MFMA (hi/lo split-precision implicit GEMM)
//     + bias/BN/ELU epilogue + fused fp32 q,k,v projections.
// Block: 256 thr = 4 waves; tile = 64 o x 32 t of one b.
// Wave w: o-half (w>>1)*32, t-half (w&1)*16. MFMA 16x16x32 bf16.
// LDS: x staged transposed [gl][c] bf16, hi+lo planes, XOR-swizzled c-groups.
// ---------------------------------------------------------------------------
__global__ __launch_bounds__(256, 2) void conv_kernel(
    const float* __restrict__ x, const unsigned short* __restrict__ wsgn,
    const float* __restrict__ scA, const float* __restrict__ scB,
    const float* __restrict__ wqT, const float* __restrict__ wkT, const float* __restrict__ wvT,
    float* __restrict__ y_out, float* __restrict__ qT, float* __restrict__ kT, float* __restrict__ vT)
{
    __shared__ __align__(16) unsigned short smem[2 * GROWS * 128];  // 77824 B
    unsigned short* xhi = smem;
    unsigned short* xlo = smem + GROWS * 128;

    int b = blockIdx.y;
    int t0 = blockIdx.x * CTT;
    int tid = threadIdx.x;

    // ---- stage x window: gl in [0,152), c in [0,128); g = 4*t0-13+gl ----
    // store transposed [gl][c] with c-group swizzle: c8' = c8 ^ ((gl>>2)&15)
    const float* xb = x + (size_t)b * CIN * TIN;
    int gbase = 4 * t0 - 13;
    for (int i = tid; i < 128 * GROWS; i += 256) {
        int c = i / GROWS, gl = i - c * GROWS;
        int g = gbase + gl;
        float v = 0.f;
        if (gl < 151 && (unsigned)g < (unsigned)TIN) v = xb[c * TIN + g];
        unsigned short h = f32_to_bf16_rne(v);
        float hf = __uint_as_float((unsigned)h << 16);
        unsigned short l = f32_to_bf16_rne(v - hf);
        int c8 = c >> 3, cl = c & 7;
        int c8p = c8 ^ ((gl >> 2) & 15);
        int off = gl * 128 + c8p * 8 + cl;
        xhi[off] = h;
        xlo[off] = l;
    }
    __syncthreads();

    // ---- MFMA K-loop ----
    int wave = tid >> 6, lane = tid & 63;
    int o0 = (wave >> 1) * 32;      // o-half base
    int tw0 = (wave & 1) * 16;      // t-half base (within 32-t tile)
    int n = lane & 15, kg = lane >> 4;

    f32x4 acc0 = {0.f, 0.f, 0.f, 0.f};
    f32x4 acc1 = {0.f, 0.f, 0.f, 0.f};

    const unsigned short* a_base = wsgn + (size_t)(o0 + n) * 128 + kg * 8;

#pragma unroll 1
    for (int kk = 0; kk < KW; ++kk) {
        int gl = 4 * (tw0 + n) + kk;
        int rot = (gl >> 2) & 15;
        const unsigned short* xh_row = xhi + gl * 128;
        const unsigned short* xl_row = xlo + gl * 128;
        const unsigned short* arow = a_base + (size_t)kk * 64 * 128;
#pragma unroll
        for (int cs = 0; cs < 4; ++cs) {
            int c8p = (cs * 4 + kg) ^ rot;
            bf16x8 bh = *(const bf16x8*)(xh_row + c8p * 8);
            bf16x8 bl = *(const bf16x8*)(xl_row + c8p * 8);
            bf16x8 a0 = *(const bf16x8*)(arow + cs * 32);
            bf16x8 a1 = *(const bf16x8*)(arow + 16 * 128 + cs * 32);
            acc0 = __builtin_amdgcn_mfma_f32_16x16x32_bf16(a0, bh, acc0, 0, 0, 0);
            acc0 = __builtin_amdgcn_mfma_f32_16x16x32_bf16(a0, bl, acc0, 0, 0, 0);
            acc1 = __builtin_amdgcn_mfma_f32_16x16x32_bf16(a1, bh, acc1, 0, 0, 0);
            acc1 = __builtin_amdgcn_mfma_f32_16x16x32_bf16(a1, bl, acc1, 0, 0, 0);
        }
    }
    __syncthreads();  // done reading x planes; reuse LDS for y tile

    // ---- epilogue: scale (alpha*BN), shift, ELU; y tile -> LDS + global ----
    // C/D layout: col = lane&15 (t), row = (lane>>4)*4 + reg (o)
    float* ysh = (float*)smem;      // [c][t] stride 33, 64*33 = 2112 floats
    int quad = lane >> 4, col = lane & 15;
    int tloc = tw0 + col;
    int t_g = t0 + tloc;
#pragma unroll
    for (int oc = 0; oc < 2; ++oc) {
        f32x4 a = oc ? acc1 : acc0;
#pragma unroll
        for (int r = 0; r < 4; ++r) {
            int o = o0 + oc * 16 + quad * 4 + r;
            float s = a[r] * scA[o] + scB[o];
            float yv = s > 0.f ? s : expm1f(s);
            ysh[o * 33 + tloc] = yv;
            if (t_g < TOUT) y_out[((size_t)b * COUT + o) * TOUT + t_g] = yv;
        }
    }
    __syncthreads();

    // ---- fused projections (fp32): q=wq@spike, k=wk@spike, v=wv@y ----
    for (int cell = tid; cell < 64 * CTT; cell += 256) {
        int oo = cell & 63, ti = cell >> 6;
        float sq = 0.f, sk = 0.f, sv = 0.f;
#pragma unroll
        for (int c = 0; c < 64; c++) {
            float yv = ysh[c * 33 + ti];
            float sp = yv > 0.f ? 1.f : 0.f;
            sq += wqT[c * 64 + oo] * sp;
            sk += wkT[c * 64 + oo] * sp;
            sv += wvT[c * 64 + oo] * yv;
        }
        int t = t0 + ti;
        if (t < TOUT) {
            size_t off = ((size_t)b * TOUT + t) * 64 + oo;
            qT[off] = sq; kT[off] = sk; vT[off] = sv;
        }
    }
}

// ---------------------------------------------------------------------------
// K2: attention per (b, 16-t tile): scores (exact, in LDS) -> softmax ->
//     ctx -> out = y + wo@ctx   (unchanged from passing version)
// ---------------------------------------------------------------------------
__global__ __launch_bounds__(256, 2) void attn_kernel(
    const float* __restrict__ qT, const float* __restrict__ kT, const float* __restrict__ vT,
    const float* __restrict__ y, const float* __restrict__ woT, float* __restrict__ out)
{
    __shared__ float sc_sh[16 * 628];
    __shared__ float kv_sh[64 * 68];
    __shared__ float qc_sh[1088];
    __shared__ float red_sh[256];
    __shared__ float rden[16];

    int b = blockIdx.y, t0 = blockIdx.x * TT, tid = threadIdx.x;
    int nt = min(TT, TOUT - t0);

    for (int idx = tid; idx < 16 * 64; idx += 256) {
        int ti = idx >> 6, c = idx & 63;
        qc_sh[ti * 64 + c] = (ti < nt) ? qT[((size_t)b * TOUT + t0 + ti) * 64 + c] : 0.f;
    }

    int ti1 = tid >> 4, sg = tid & 15;

    for (int s0 = 0; s0 < TOUT; s0 += 64) {
        int ns = min(64, TOUT - s0);
        __syncthreads();
        for (int idx = tid; idx < 64 * 64; idx += 256) {
            int c = idx >> 6, si = idx & 63;
            kv_sh[c * 68 + si] = (si < ns) ? kT[((size_t)b * TOUT + s0 + si) * 64 + c] : 0.f;
        }
        __syncthreads();
        float a0 = 0, a1 = 0, a2 = 0, a3 = 0;
        const float* qrow = &qc_sh[ti1 * 64];
#pragma unroll
        for (int c = 0; c < 64; c++) {
            float qv = qrow[c];
            float4 k4 = *(const float4*)&kv_sh[c * 68 + sg * 4];
            a0 += qv * k4.x; a1 += qv * k4.y; a2 += qv * k4.z; a3 += qv * k4.w;
        }
        float4 r;
        r.x = a0 * 0.125f; r.y = a1 * 0.125f; r.z = a2 * 0.125f; r.w = a3 * 0.125f;
        *(float4*)&sc_sh[ti1 * 628 + s0 + sg * 4] = r;
    }
    __syncthreads();

    float mx = -3.0e38f;
    for (int s = sg; s < TOUT; s += 16) mx = fmaxf(mx, sc_sh[ti1 * 628 + s]);
    red_sh[tid] = mx;
    __syncthreads();
    float rowm = red_sh[ti1 * 16];
#pragma unroll
    for (int l = 1; l < 16; l++) rowm = fmaxf(rowm, red_sh[ti1 * 16 + l]);
    __syncthreads();
    float sum = 0.f;
    for (int s = sg; s < TOUT; s += 16) {
        float e = __expf(sc_sh[ti1 * 628 + s] - rowm);
        sc_sh[ti1 * 628 + s] = e;
        sum += e;
    }
    red_sh[tid] = sum;
    __syncthreads();
    if (tid < 16) {
        float tot = 0.f;
#pragma unroll
        for (int l = 0; l < 16; l++) tot += red_sh[tid * 16 + l];
        rden[tid] = 1.f / tot;
    }

    int cc = tid & 63, tg = tid >> 6;
    float ctx0 = 0, ctx1 = 0, ctx2 = 0, ctx3 = 0;
    for (int s0 = 0; s0 < TOUT; s0 += 64) {
        int ns = min(64, TOUT - s0);
        __syncthreads();
        for (int idx = tid; idx < 64 * 64; idx += 256) {
            int si = idx >> 6, c = idx & 63;
            kv_sh[si * 64 + c] = (si < ns) ? vT[((size_t)b * TOUT + s0 + si) * 64 + c] : 0.f;
        }
        __syncthreads();
        const float* srow = &sc_sh[(tg * 4) * 628 + s0];
#pragma unroll 1
        for (int si = 0; si < 64; si++) {
            float vv = kv_sh[si * 64 + cc];
            ctx0 += srow[si] * vv;
            ctx1 += srow[628 + si] * vv;
            ctx2 += srow[1256 + si] * vv;
            ctx3 += srow[1884 + si] * vv;
        }
    }

    __syncthreads();
    float* ctx_sh = qc_sh;
    ctx_sh[cc * 17 + tg * 4 + 0] = ctx0 * rden[tg * 4 + 0];
    ctx_sh[cc * 17 + tg * 4 + 1] = ctx1 * rden[tg * 4 + 1];
    ctx_sh[cc * 17 + tg * 4 + 2] = ctx2 * rden[tg * 4 + 2];
    ctx_sh[cc * 17 + tg * 4 + 3] = ctx3 * rden[tg * 4 + 3];
    __syncthreads();
    for (int cell = tid; cell < 64 * TT; cell += 256) {
        int oo = cell >> 4, ti = cell & 15;
        if (ti < nt) {
            float acc = 0.f;
#pragma unroll
            for (int c = 0; c < 64; c++) acc += woT[c * 64 + oo] * ctx_sh[c * 17 + ti];
            size_t off = ((size_t)b * COUT + oo) * TOUT + t0 + ti;
            out[off] = y[off] + acc;
        }
    }
}

// ---------------------------------------------------------------------------
extern "C" void kernel_launch(void* const* d_in, const int* in_sizes, int n_in,
                              void* d_out, int out_size, void* d_ws, size_t ws_size,
                              hipStream_t stream) {
    const float* x        = (const float*)d_in[0];
    const float* conv_w   = (const float*)d_in[1];
    const float* conv_b   = (const float*)d_in[2];
    const float* bn_gamma = (const float*)d_in[3];
    const float* bn_beta  = (const float*)d_in[4];
    const float* bn_mean  = (const float*)d_in[5];
    const float* bn_var   = (const float*)d_in[6];
    const float* wq       = (const float*)d_in[7];
    const float* wk       = (const float*)d_in[8];
    const float* wv       = (const float*)d_in[9];
    const float* wo       = (const float*)d_in[10];
    float* out = (float*)d_out;
    float* ws  = (float*)d_ws;

    // ws layout (float offsets).
    // wsgn = 27*64*128 ushorts = 221184 ushorts = 110592 FLOATS (round-2 bug:
    // had budgeted 55296 floats -> binarize overwrote alpha/scA/scB/wT4/yb).
    unsigned short* wsgn = (unsigned short*)ws;   // floats [0, 110592)
    float* alpha = ws + 110592;                   // 64
    float* scA   = ws + 110656;                   // 64
    float* scB   = ws + 110720;                   // 64 (pad to 110848)
    float* wT4   = ws + 110848;                   // 4*4096 -> ends 127232
    float* yb    = ws + 131072;                   // 5120000  y[b][o][t]
    float* qTp   = ws + 5251072;                  // 5120000  q[b][t][c]
    float* kTp   = ws + 10371072;                 // 5120000
    float* vTp   = ws + 15491072;                 // 5120000 -> ends 20611072

    hipLaunchKernelGGL(binarize_kernel, dim3(64), dim3(256), 0, stream, conv_w, wsgn, alpha);
    hipLaunchKernelGGL(transpose_w_kernel, dim3(5), dim3(256), 0, stream,
                       wq, wk, wv, wo, conv_b, bn_gamma, bn_beta, bn_mean, bn_var, alpha,
                       wT4, scA, scB);
    hipLaunchKernelGGL(conv_kernel, dim3(20, 128), dim3(256), 0, stream,
                       x, wsgn, scA, scB, wT4, wT4 + 4096, wT4 + 8192,
                       yb, qTp, kTp, vTp);
    hipLaunchKernelGGL(attn_kernel, dim3(40, 128), dim3(256), 0, stream,
                       qTp, kTp, vTp, yb, wT4 + 12288, out);
}

// Round 4
// 3399.492 us; speedup vs baseline: 1.1922x; 1.0968x over previous
//
#include <hip/hip_runtime.h>
#include <math.h>

#define B_    128
#define CIN   128
#define TIN   2500
#define COUT  64
#define KW    27
#define TOUT  625
#define TT    16    // attn t-tile
#define CTT   32    // conv t-tile
#define GROWS 152   // conv staging rows (span 4*31+27=151, pad to 152)

typedef __bf16 bf16x8 __attribute__((ext_vector_type(8)));
typedef float  f32x4  __attribute__((ext_vector_type(4)));

__device__ __forceinline__ unsigned short f32_to_bf16_rne(float v) {
    unsigned u = __float_as_uint(v);
    u += 0x7FFFu + ((u >> 16) & 1u);
    return (unsigned short)(u >> 16);
}

// expand 8 sign bits (bit=1 => -1.0, bit=0 => +1.0) into bf16x8 of +-1.0
__device__ __forceinline__ bf16x8 expand_sgn(unsigned b) {
    union { unsigned u[4]; bf16x8 v; } r;
#pragma unroll
    for (int j = 0; j < 4; j++) {
        unsigned lo = (b >> (2 * j)) & 1u;
        unsigned hi = (b >> (2 * j + 1)) & 1u;
        r.u[j] = 0x3F803F80u | (lo << 15) | (hi << 31);
    }
    return r.v;
}

// ---------------------------------------------------------------------------
// K0: alpha[o] = mean|w|; packed sign bits:
//     sgn2[(kk*4+kg)*64 + o] = u32, byte cs holds bits j for c = cs*32+kg*8+j
//     bit = 1 iff w <= 0 (negative => bf16 -1.0)
// ---------------------------------------------------------------------------
__global__ void binarize_kernel(const float* __restrict__ w,
                                unsigned* __restrict__ sgn2,
                                float* __restrict__ alpha_out) {
    int o = blockIdx.x, tid = threadIdx.x;
    __shared__ float red[256];
    const float* wo_ = w + (size_t)o * (CIN * KW);
    float s = 0.f;
    for (int idx = tid; idx < CIN * KW; idx += 256) s += fabsf(wo_[idx]);
    red[tid] = s;
    __syncthreads();
    for (int st = 128; st > 0; st >>= 1) {
        if (tid < st) red[tid] += red[tid + st];
        __syncthreads();
    }
    if (tid == 0) alpha_out[o] = red[0] / (float)(CIN * KW);

    for (int t = tid; t < KW * 4; t += 256) {
        int kk = t >> 2, kg = t & 3;
        unsigned u = 0;
#pragma unroll
        for (int cs = 0; cs < 4; cs++) {
#pragma unroll
            for (int j = 0; j < 8; j++) {
                int c = cs * 32 + kg * 8 + j;
                float v = wo_[c * KW + kk];
                unsigned bit = (v > 0.f) ? 0u : 1u;
                u |= bit << (cs * 8 + j);
            }
        }
        sgn2[(kk * 4 + kg) * 64 + o] = u;
    }
}

// ---------------------------------------------------------------------------
// K0b: transpose 4 projection mats; block 4 folds alpha+bias+BN into scA/scB
// ---------------------------------------------------------------------------
__global__ void transpose_w_kernel(const float* __restrict__ wq, const float* __restrict__ wk,
                                   const float* __restrict__ wv, const float* __restrict__ wo,
                                   const float* __restrict__ conv_b, const float* __restrict__ gamma_,
                                   const float* __restrict__ beta_, const float* __restrict__ mean_,
                                   const float* __restrict__ var_, const float* __restrict__ alpha_,
                                   float* __restrict__ dstT, float* __restrict__ scA, float* __restrict__ scB) {
    if (blockIdx.x < 4) {
        const float* srcs[4] = {wq, wk, wv, wo};
        const float* src = srcs[blockIdx.x];
        float* dst = dstT + (size_t)blockIdx.x * 4096;
        for (int idx = threadIdx.x; idx < 4096; idx += 256) {
            int o = idx >> 6, c = idx & 63;
            dst[c * 64 + o] = src[idx];
        }
    } else {
        int o = threadIdx.x;
        if (o < 64) {
            float inv = rsqrtf(var_[o] + 1e-5f);
            float G = gamma_[o] * inv;
            scA[o] = alpha_[o] * G;
            scB[o] = (conv_b[o] - mean_[o]) * G + beta_[o];
        }
    }
}

// ---------------------------------------------------------------------------
// K1: binarized conv1d via bf16 MFMA, A-operand expanded in-register from
//     L1-resident packed sign bits. x staged hi/lo bf16 in LDS (b128 writes).
// Block: 256 thr = 4 waves; tile = 64 o x 32 t of one b.
// Wave w: o-half (w>>1)*32, t-half (w&1)*16. MFMA 16x16x32 bf16.
// ---------------------------------------------------------------------------
__global__ __launch_bounds__(256, 2) void conv_kernel(
    const float* __restrict__ x, const unsigned* __restrict__ sgn2,
    const float* __restrict__ scA, const float* __restrict__ scB,
    const float* __restrict__ wqT, const float* __restrict__ wkT, const float* __restrict__ wvT,
    float* __restrict__ y_out, float* __restrict__ qT, float* __restrict__ kT, float* __restrict__ vT)
{
    __shared__ __align__(16) unsigned short smem[2 * GROWS * 128];  // 77824 B
    unsigned short* xhi = smem;
    unsigned short* xlo = smem + GROWS * 128;

    int b = blockIdx.y;
    int t0 = blockIdx.x * CTT;
    int tid = threadIdx.x;

    // ---- stage x: task = (c8, gl); 8 coalesced loads -> b128 hi + b128 lo ----
    const float* xb = x + (size_t)b * CIN * TIN;
    int gbase = 4 * t0 - 13;
    for (int task = tid; task < 16 * GROWS; task += 256) {
        int c8 = task / GROWS, gl = task - c8 * GROWS;
        int g = gbase + gl;
        bool valid = (gl < 151) && ((unsigned)g < (unsigned)TIN);
        float vs[8];
#pragma unroll
        for (int j = 0; j < 8; j++)
            vs[j] = valid ? xb[(size_t)(c8 * 8 + j) * TIN + g] : 0.f;
        union { unsigned u[4]; uint4 q; } H, L;
#pragma unroll
        for (int j = 0; j < 4; j++) {
            unsigned short h0 = f32_to_bf16_rne(vs[2 * j]);
            unsigned short h1 = f32_to_bf16_rne(vs[2 * j + 1]);
            float hf0 = __uint_as_float((unsigned)h0 << 16);
            float hf1 = __uint_as_float((unsigned)h1 << 16);
            unsigned short l0 = f32_to_bf16_rne(vs[2 * j] - hf0);
            unsigned short l1 = f32_to_bf16_rne(vs[2 * j + 1] - hf1);
            H.u[j] = (unsigned)h0 | ((unsigned)h1 << 16);
            L.u[j] = (unsigned)l0 | ((unsigned)l1 << 16);
        }
        int c8p = c8 ^ ((gl >> 2) & 15);
        int off = gl * 128 + c8p * 8;
        *(uint4*)(xhi + off) = H.q;
        *(uint4*)(xlo + off) = L.q;
    }
    __syncthreads();

    // ---- MFMA K-loop ----
    int wave = tid >> 6, lane = tid & 63;
    int o0 = (wave >> 1) * 32;      // o-half base
    int tw0 = (wave & 1) * 16;      // t-half base (within 32-t tile)
    int n = lane & 15, kg = lane >> 4;

    f32x4 acc0 = {0.f, 0.f, 0.f, 0.f};
    f32x4 acc1 = {0.f, 0.f, 0.f, 0.f};

    // per-lane packed-sign pointers: idx = (kk*4+kg)*64 + o0 + n  (stride 256/kk)
    const unsigned* sg_base = sgn2 + (size_t)kg * 64 + o0 + n;
    unsigned sa0 = sg_base[0];     // kk=0, a0 rows
    unsigned sa1 = sg_base[16];    // kk=0, a1 rows (o+16)

#pragma unroll 1
    for (int kk = 0; kk < KW; ++kk) {
        unsigned na0 = 0, na1 = 0;
        if (kk < KW - 1) {          // prefetch next kk's sign words (L1-hot)
            na0 = sg_base[(kk + 1) * 256];
            na1 = sg_base[(kk + 1) * 256 + 16];
        }
        int gl = 4 * (tw0 + n) + kk;
        int rot = (gl >> 2) & 15;
        const unsigned short* xh_row = xhi + gl * 128;
        const unsigned short* xl_row = xlo + gl * 128;
#pragma unroll
        for (int cs = 0; cs < 4; ++cs) {
            int c8p = (cs * 4 + kg) ^ rot;
            bf16x8 bh = *(const bf16x8*)(xh_row + c8p * 8);
            bf16x8 bl = *(const bf16x8*)(xl_row + c8p * 8);
            bf16x8 a0 = expand_sgn((sa0 >> (8 * cs)) & 0xFFu);
            bf16x8 a1 = expand_sgn((sa1 >> (8 * cs)) & 0xFFu);
            acc0 = __builtin_amdgcn_mfma_f32_16x16x32_bf16(a0, bh, acc0, 0, 0, 0);
            acc0 = __builtin_amdgcn_mfma_f32_16x16x32_bf16(a0, bl, acc0, 0, 0, 0);
            acc1 = __builtin_amdgcn_mfma_f32_16x16x32_bf16(a1, bh, acc1, 0, 0, 0);
            acc1 = __builtin_amdgcn_mfma_f32_16x16x32_bf16(a1, bl, acc1, 0, 0, 0);
        }
        sa0 = na0; sa1 = na1;
    }
    __syncthreads();  // done reading x planes; reuse LDS for y tile

    // ---- epilogue: scale (alpha*BN), shift, ELU; y tile -> LDS + global ----
    // C/D layout: col = lane&15 (t), row = (lane>>4)*4 + reg (o)
    float* ysh = (float*)smem;      // [c][t] stride 33, 64*33 = 2112 floats
    int quad = lane >> 4, col = lane & 15;
    int tloc = tw0 + col;
    int t_g = t0 + tloc;
#pragma unroll
    for (int oc = 0; oc < 2; ++oc) {
        f32x4 a = oc ? acc1 : acc0;
#pragma unroll
        for (int r = 0; r < 4; ++r) {
            int o = o0 + oc * 16 + quad * 4 + r;
            float s = a[r] * scA[o] + scB[o];
            float yv = s > 0.f ? s : expm1f(s);
            ysh[o * 33 + tloc] = yv;
            if (t_g < TOUT) y_out[((size_t)b * COUT + o) * TOUT + t_g] = yv;
        }
    }
    __syncthreads();

    // ---- fused projections (fp32): q=wq@spike, k=wk@spike, v=wv@y ----
    for (int cell = tid; cell < 64 * CTT; cell += 256) {
        int oo = cell & 63, ti = cell >> 6;
        float sq = 0.f, sk = 0.f, sv = 0.f;
#pragma unroll
        for (int c = 0; c < 64; c++) {
            float yv = ysh[c * 33 + ti];
            float sp = yv > 0.f ? 1.f : 0.f;
            sq += wqT[c * 64 + oo] * sp;
            sk += wkT[c * 64 + oo] * sp;
            sv += wvT[c * 64 + oo] * yv;
        }
        int t = t0 + ti;
        if (t < TOUT) {
            size_t off = ((size_t)b * TOUT + t) * 64 + oo;
            qT[off] = sq; kT[off] = sk; vT[off] = sv;
        }
    }
}

// ---------------------------------------------------------------------------
// K2: attention per (b, 16-t tile): scores (exact, in LDS) -> softmax ->
//     ctx -> out = y + wo@ctx   (unchanged)
// ---------------------------------------------------------------------------
__global__ __launch_bounds__(256, 2) void attn_kernel(
    const float* __restrict__ qT, const float* __restrict__ kT, const float* __restrict__ vT,
    const float* __restrict__ y, const float* __restrict__ woT, float* __restrict__ out)
{
    __shared__ float sc_sh[16 * 628];
    __shared__ float kv_sh[64 * 68];
    __shared__ float qc_sh[1088];
    __shared__ float red_sh[256];
    __shared__ float rden[16];

    int b = blockIdx.y, t0 = blockIdx.x * TT, tid = threadIdx.x;
    int nt = min(TT, TOUT - t0);

    for (int idx = tid; idx < 16 * 64; idx += 256) {
        int ti = idx >> 6, c = idx & 63;
        qc_sh[ti * 64 + c] = (ti < nt) ? qT[((size_t)b * TOUT + t0 + ti) * 64 + c] : 0.f;
    }

    int ti1 = tid >> 4, sg = tid & 15;

    for (int s0 = 0; s0 < TOUT; s0 += 64) {
        int ns = min(64, TOUT - s0);
        __syncthreads();
        for (int idx = tid; idx < 64 * 64; idx += 256) {
            int c = idx >> 6, si = idx & 63;
            kv_sh[c * 68 + si] = (si < ns) ? kT[((size_t)b * TOUT + s0 + si) * 64 + c] : 0.f;
        }
        __syncthreads();
        float a0 = 0, a1 = 0, a2 = 0, a3 = 0;
        const float* qrow = &qc_sh[ti1 * 64];
#pragma unroll
        for (int c = 0; c < 64; c++) {
            float qv = qrow[c];
            float4 k4 = *(const float4*)&kv_sh[c * 68 + sg * 4];
            a0 += qv * k4.x; a1 += qv * k4.y; a2 += qv * k4.z; a3 += qv * k4.w;
        }
        float4 r;
        r.x = a0 * 0.125f; r.y = a1 * 0.125f; r.z = a2 * 0.125f; r.w = a3 * 0.125f;
        *(float4*)&sc_sh[ti1 * 628 + s0 + sg * 4] = r;
    }
    __syncthreads();

    float mx = -3.0e38f;
    for (int s = sg; s < TOUT; s += 16) mx = fmaxf(mx, sc_sh[ti1 * 628 + s]);
    red_sh[tid] = mx;
    __syncthreads();
    float rowm = red_sh[ti1 * 16];
#pragma unroll
    for (int l = 1; l < 16; l++) rowm = fmaxf(rowm, red_sh[ti1 * 16 + l]);
    __syncthreads();
    float sum = 0.f;
    for (int s = sg; s < TOUT; s += 16) {
        float e = __expf(sc_sh[ti1 * 628 + s] - rowm);
        sc_sh[ti1 * 628 + s] = e;
        sum += e;
    }
    red_sh[tid] = sum;
    __syncthreads();
    if (tid < 16) {
        float tot = 0.f;
#pragma unroll
        for (int l = 0; l < 16; l++) tot += red_sh[tid * 16 + l];
        rden[tid] = 1.f / tot;
    }

    int cc = tid & 63, tg = tid >> 6;
    float ctx0 = 0, ctx1 = 0, ctx2 = 0, ctx3 = 0;
    for (int s0 = 0; s0 < TOUT; s0 += 64) {
        int ns = min(64, TOUT - s0);
        __syncthreads();
        for (int idx = tid; idx < 64 * 64; idx += 256) {
            int si = idx >> 6, c = idx & 63;
            kv_sh[si * 64 + c] = (si < ns) ? vT[((size_t)b * TOUT + s0 + si) * 64 + c] : 0.f;
        }
        __syncthreads();
        const float* srow = &sc_sh[(tg * 4) * 628 + s0];
#pragma unroll 1
        for (int si = 0; si < 64; si++) {
            float vv = kv_sh[si * 64 + cc];
            ctx0 += srow[si] * vv;
            ctx1 += srow[628 + si] * vv;
            ctx2 += srow[1256 + si] * vv;
            ctx3 += srow[1884 + si] * vv;
        }
    }

    __syncthreads();
    float* ctx_sh = qc_sh;
    ctx_sh[cc * 17 + tg * 4 + 0] = ctx0 * rden[tg * 4 + 0];
    ctx_sh[cc * 17 + tg * 4 + 1] = ctx1 * rden[tg * 4 + 1];
    ctx_sh[cc * 17 + tg * 4 + 2] = ctx2 * rden[tg * 4 + 2];
    ctx_sh[cc * 17 + tg * 4 + 3] = ctx3 * rden[tg * 4 + 3];
    __syncthreads();
    for (int cell = tid; cell < 64 * TT; cell += 256) {
        int oo = cell >> 4, ti = cell & 15;
        if (ti < nt) {
            float acc = 0.f;
#pragma unroll
            for (int c = 0; c < 64; c++) acc += woT[c * 64 + oo] * ctx_sh[c * 17 + ti];
            size_t off = ((size_t)b * COUT + oo) * TOUT + t0 + ti;
            out[off] = y[off] + acc;
        }
    }
}

// ---------------------------------------------------------------------------
extern "C" void kernel_launch(void* const* d_in, const int* in_sizes, int n_in,
                              void* d_out, int out_size, void* d_ws, size_t ws_size,
                              hipStream_t stream) {
    const float* x        = (const float*)d_in[0];
    const float* conv_w   = (const float*)d_in[1];
    const float* conv_b   = (const float*)d_in[2];
    const float* bn_gamma = (const float*)d_in[3];
    const float* bn_beta  = (const float*)d_in[4];
    const float* bn_mean  = (const float*)d_in[5];
    const float* bn_var   = (const float*)d_in[6];
    const float* wq       = (const float*)d_in[7];
    const float* wk       = (const float*)d_in[8];
    const float* wv       = (const float*)d_in[9];
    const float* wo       = (const float*)d_in[10];
    float* out = (float*)d_out;
    float* ws  = (float*)d_ws;

    // ws layout (float offsets) — offsets kept from the passing R3 layout
    unsigned* sgn2 = (unsigned*)ws;               // 27*4*64 u32 = 6912 floats
    float* alpha = ws + 110592;                   // 64
    float* scA   = ws + 110656;                   // 64
    float* scB   = ws + 110720;                   // 64
    float* wT4   = ws + 110848;                   // 4*4096
    float* yb    = ws + 131072;                   // 5120000  y[b][o][t]
    float* qTp   = ws + 5251072;                  // 5120000  q[b][t][c]
    float* kTp   = ws + 10371072;                 // 5120000
    float* vTp   = ws + 15491072;                 // 5120000

    hipLaunchKernelGGL(binarize_kernel, dim3(64), dim3(256), 0, stream, conv_w, sgn2, alpha);
    hipLaunchKernelGGL(transpose_w_kernel, dim3(5), dim3(256), 0, stream,
                       wq, wk, wv, wo, conv_b, bn_gamma, bn_beta, bn_mean, bn_var, alpha,
                       wT4, scA, scB);
    hipLaunchKernelGGL(conv_kernel, dim3(20, 128), dim3(256), 0, stream,
                       x, sgn2, scA, scB, wT4, wT4 + 4096, wT4 + 8192,
                       yb, qTp, kTp, vTp);
    hipLaunchKernelGGL(attn_kernel, dim3(40, 128), dim3(256), 0, stream,
                       qTp, kTp, vTp, yb, wT4 + 12288, out);
}

// Round 5
// 584.721 us; speedup vs baseline: 6.9310x; 5.8139x over previous
//
#include <hip/hip_runtime.h>
#include <math.h>

#define B_    128
#define CIN   128
#define TIN   2500
#define COUT  64
#define KW    27
#define TOUT  625
#define TPAD  640   // padded t extent for bf16 q/k/v planes
#define CTT   32    // conv t-tile
#define GROWS 152   // conv staging rows (span 4*31+27=151, pad to 152)

typedef __bf16 bf16x8 __attribute__((ext_vector_type(8)));
typedef float  f32x4  __attribute__((ext_vector_type(4)));

__device__ __forceinline__ unsigned short f32_to_bf16_rne(float v) {
    unsigned u = __float_as_uint(v);
    u += 0x7FFFu + ((u >> 16) & 1u);
    return (unsigned short)(u >> 16);
}

__device__ __forceinline__ f32x4 mfma_bf16(bf16x8 a, bf16x8 b, f32x4 c) {
    return __builtin_amdgcn_mfma_f32_16x16x32_bf16(a, b, c, 0, 0, 0);
}

// expand 8 sign bits (bit=1 => -1.0, bit=0 => +1.0) into bf16x8 of +-1.0
__device__ __forceinline__ bf16x8 expand_sgn(unsigned b) {
    union { unsigned u[4]; bf16x8 v; } r;
#pragma unroll
    for (int j = 0; j < 4; j++) {
        unsigned lo = (b >> (2 * j)) & 1u;
        unsigned hi = (b >> (2 * j + 1)) & 1u;
        r.u[j] = 0x3F803F80u | (lo << 15) | (hi << 31);
    }
    return r.v;
}

// ---------------------------------------------------------------------------
// K0: alpha[o] = mean|w|; packed sign bits:
//     sgn2[(kk*4+kg)*64 + o] = u32, byte cs holds bits j for c = cs*32+kg*8+j
// ---------------------------------------------------------------------------
__global__ void binarize_kernel(const float* __restrict__ w,
                                unsigned* __restrict__ sgn2,
                                float* __restrict__ alpha_out) {
    int o = blockIdx.x, tid = threadIdx.x;
    __shared__ float red[256];
    const float* wo_ = w + (size_t)o * (CIN * KW);
    float s = 0.f;
    for (int idx = tid; idx < CIN * KW; idx += 256) s += fabsf(wo_[idx]);
    red[tid] = s;
    __syncthreads();
    for (int st = 128; st > 0; st >>= 1) {
        if (tid < st) red[tid] += red[tid + st];
        __syncthreads();
    }
    if (tid == 0) alpha_out[o] = red[0] / (float)(CIN * KW);

    for (int t = tid; t < KW * 4; t += 256) {
        int kk = t >> 2, kg = t & 3;
        unsigned u = 0;
#pragma unroll
        for (int cs = 0; cs < 4; cs++) {
#pragma unroll
            for (int j = 0; j < 8; j++) {
                int c = cs * 32 + kg * 8 + j;
                float v = wo_[c * KW + kk];
                unsigned bit = (v > 0.f) ? 0u : 1u;
                u |= bit << (cs * 8 + j);
            }
        }
        sgn2[(kk * 4 + kg) * 64 + o] = u;
    }
}

// ---------------------------------------------------------------------------
// K0b: blocks 0-2: transpose wq/wk/wv -> wT[c][o]; block 3: wo -> bf16 hi/lo
//      [o][c]; block 4: fold alpha+bias+BN into scA/scB
// ---------------------------------------------------------------------------
__global__ void transpose_w_kernel(const float* __restrict__ wq, const float* __restrict__ wk,
                                   const float* __restrict__ wv, const float* __restrict__ wo,
                                   const float* __restrict__ conv_b, const float* __restrict__ gamma_,
                                   const float* __restrict__ beta_, const float* __restrict__ mean_,
                                   const float* __restrict__ var_, const float* __restrict__ alpha_,
                                   float* __restrict__ dstT,
                                   unsigned short* __restrict__ wo_h, unsigned short* __restrict__ wo_l,
                                   float* __restrict__ scA, float* __restrict__ scB) {
    if (blockIdx.x < 3) {
        const float* srcs[3] = {wq, wk, wv};
        const float* src = srcs[blockIdx.x];
        float* dst = dstT + (size_t)blockIdx.x * 4096;
        for (int idx = threadIdx.x; idx < 4096; idx += 256) {
            int o = idx >> 6, c = idx & 63;
            dst[c * 64 + o] = src[idx];
        }
    } else if (blockIdx.x == 3) {
        for (int idx = threadIdx.x; idx < 4096; idx += 256) {
            float v = wo[idx];
            unsigned short h = f32_to_bf16_rne(v);
            float hf = __uint_as_float((unsigned)h << 16);
            wo_h[idx] = h;
            wo_l[idx] = f32_to_bf16_rne(v - hf);
        }
    } else {
        int o = threadIdx.x;
        if (o < 64) {
            float inv = rsqrtf(var_[o] + 1e-5f);
            float G = gamma_[o] * inv;
            scA[o] = alpha_[o] * G;
            scB[o] = (conv_b[o] - mean_[o]) * G + beta_[o];
        }
    }
}

// ---------------------------------------------------------------------------
// K1: binarized conv1d via bf16 MFMA (hi/lo split) + BN/ELU -> y only.
//     (projection phase removed -> proj_kernel)
// ---------------------------------------------------------------------------
__global__ __launch_bounds__(256, 2) void conv_kernel(
    const float* __restrict__ x, const unsigned* __restrict__ sgn2,
    const float* __restrict__ scA, const float* __restrict__ scB,
    float* __restrict__ y_out)
{
    __shared__ __align__(16) unsigned short smem[2 * GROWS * 128];  // 77824 B
    unsigned short* xhi = smem;
    unsigned short* xlo = smem + GROWS * 128;

    int b = blockIdx.y;
    int t0 = blockIdx.x * CTT;
    int tid = threadIdx.x;

    const float* xb = x + (size_t)b * CIN * TIN;
    int gbase = 4 * t0 - 13;
    for (int task = tid; task < 16 * GROWS; task += 256) {
        int c8 = task / GROWS, gl = task - c8 * GROWS;
        int g = gbase + gl;
        bool valid = (gl < 151) && ((unsigned)g < (unsigned)TIN);
        float vs[8];
#pragma unroll
        for (int j = 0; j < 8; j++)
            vs[j] = valid ? xb[(size_t)(c8 * 8 + j) * TIN + g] : 0.f;
        union { unsigned u[4]; uint4 q; } H, L;
#pragma unroll
        for (int j = 0; j < 4; j++) {
            unsigned short h0 = f32_to_bf16_rne(vs[2 * j]);
            unsigned short h1 = f32_to_bf16_rne(vs[2 * j + 1]);
            float hf0 = __uint_as_float((unsigned)h0 << 16);
            float hf1 = __uint_as_float((unsigned)h1 << 16);
            unsigned short l0 = f32_to_bf16_rne(vs[2 * j] - hf0);
            unsigned short l1 = f32_to_bf16_rne(vs[2 * j + 1] - hf1);
            H.u[j] = (unsigned)h0 | ((unsigned)h1 << 16);
            L.u[j] = (unsigned)l0 | ((unsigned)l1 << 16);
        }
        int c8p = c8 ^ ((gl >> 2) & 15);
        int off = gl * 128 + c8p * 8;
        *(uint4*)(xhi + off) = H.q;
        *(uint4*)(xlo + off) = L.q;
    }
    __syncthreads();

    int wave = tid >> 6, lane = tid & 63;
    int o0 = (wave >> 1) * 32;
    int tw0 = (wave & 1) * 16;
    int n = lane & 15, kg = lane >> 4;

    f32x4 acc0 = {0.f, 0.f, 0.f, 0.f};
    f32x4 acc1 = {0.f, 0.f, 0.f, 0.f};

    const unsigned* sg_base = sgn2 + (size_t)kg * 64 + o0 + n;
    unsigned sa0 = sg_base[0];
    unsigned sa1 = sg_base[16];

#pragma unroll 1
    for (int kk = 0; kk < KW; ++kk) {
        unsigned na0 = 0, na1 = 0;
        if (kk < KW - 1) {
            na0 = sg_base[(kk + 1) * 256];
            na1 = sg_base[(kk + 1) * 256 + 16];
        }
        int gl = 4 * (tw0 + n) + kk;
        int rot = (gl >> 2) & 15;
        const unsigned short* xh_row = xhi + gl * 128;
        const unsigned short* xl_row = xlo + gl * 128;
#pragma unroll
        for (int cs = 0; cs < 4; ++cs) {
            int c8p = (cs * 4 + kg) ^ rot;
            bf16x8 bh = *(const bf16x8*)(xh_row + c8p * 8);
            bf16x8 bl = *(const bf16x8*)(xl_row + c8p * 8);
            bf16x8 a0 = expand_sgn((sa0 >> (8 * cs)) & 0xFFu);
            bf16x8 a1 = expand_sgn((sa1 >> (8 * cs)) & 0xFFu);
            acc0 = mfma_bf16(a0, bh, acc0);
            acc0 = mfma_bf16(a0, bl, acc0);
            acc1 = mfma_bf16(a1, bh, acc1);
            acc1 = mfma_bf16(a1, bl, acc1);
        }
        sa0 = na0; sa1 = na1;
    }

    // epilogue: C col = lane&15 (t), row = quad*4+r (o); write y directly
    int quad = lane >> 4, col = lane & 15;
    int t_g = t0 + tw0 + col;
    if (t_g < TOUT) {
#pragma unroll
        for (int oc = 0; oc < 2; ++oc) {
            f32x4 a = oc ? acc1 : acc0;
#pragma unroll
            for (int r = 0; r < 4; ++r) {
                int o = o0 + oc * 16 + quad * 4 + r;
                float s = a[r] * scA[o] + scB[o];
                float yv = s > 0.f ? s : expm1f(s);
                y_out[((size_t)b * COUT + o) * TOUT + t_g] = yv;
            }
        }
    }
}

// ---------------------------------------------------------------------------
// K1b: projections q=wq@spike(y), k=wk@spike(y), v=wv@y as tiled GEMM.
//   Outputs bf16: q_h,k_h [b][t(640)][c]; vT_h [b][c][t(640)]. Pad t>=625 -> 0.
//   Block: 256 thr, tile 128 t. Thread (oo=tid&63, tq=tid>>6) -> 32 t.
// ---------------------------------------------------------------------------
__global__ __launch_bounds__(256, 2) void proj_kernel(
    const float* __restrict__ y, const float* __restrict__ wqT,
    const float* __restrict__ wkT, const float* __restrict__ wvT,
    unsigned short* __restrict__ q_h, unsigned short* __restrict__ k_h,
    unsigned short* __restrict__ vT_h)
{
    __shared__ float y_sh[64 * 132];   // stride 132, 33792 B
    int b = blockIdx.y, t0 = blockIdx.x * 128, tid = threadIdx.x;

    const float* yb = y + (size_t)b * COUT * TOUT;
    for (int i = tid; i < 64 * 128; i += 256) {
        int c = i >> 7, tt = i & 127;
        int t = t0 + tt;
        y_sh[c * 132 + tt] = (t < TOUT) ? yb[c * TOUT + t] : 0.f;
    }
    __syncthreads();

    int oo = tid & 63, tq = tid >> 6;
    float q[32], k[32], v[32];
#pragma unroll
    for (int j = 0; j < 32; j++) { q[j] = 0.f; k[j] = 0.f; v[j] = 0.f; }

#pragma unroll 1
    for (int c = 0; c < 64; ++c) {
        float wq = wqT[c * 64 + oo];
        float wk = wkT[c * 64 + oo];
        float wv = wvT[c * 64 + oo];
        const float* yr = &y_sh[c * 132 + tq * 32];
#pragma unroll
        for (int j = 0; j < 32; ++j) {
            float yv = yr[j];
            float sp = yv > 0.f ? 1.f : 0.f;
            q[j] += wq * sp; k[j] += wk * sp; v[j] += wv * yv;
        }
    }

    int tbase = t0 + tq * 32;
    // q,k: [b][t][c], lanes cover consecutive c -> coalesced
#pragma unroll
    for (int j = 0; j < 32; ++j) {
        size_t off = ((size_t)b * TPAD + tbase + j) * 64 + oo;
        q_h[off] = f32_to_bf16_rne(q[j]);
        k_h[off] = f32_to_bf16_rne(k[j]);
    }
    // vT: [b][c][t], per-thread contiguous 64 B
    union { unsigned short u[32]; uint4 q4[4]; } V;
#pragma unroll
    for (int j = 0; j < 32; ++j) V.u[j] = f32_to_bf16_rne(v[j]);
    unsigned short* vp = vT_h + ((size_t)b * 64 + oo) * TPAD + tbase;
#pragma unroll
    for (int i = 0; i < 4; i++) ((uint4*)vp)[i] = V.q4[i];
}

// ---------------------------------------------------------------------------
// K2: MFMA attention per (b, 16-t tile).
//   scores: S(16x640) = Q @ K^T via MFMA, frags direct from global bf16.
//   softmax: proven 2-pass fp32 in LDS (stride 648).
//   PV: ctx = P @ V via MFMA (P fp32->bf16 from LDS, V frags direct global).
//   epilogue: out = y + wo @ ctx via MFMA (wo hi/lo bf16).
// ---------------------------------------------------------------------------
__global__ __launch_bounds__(256, 3) void attn_kernel(
    const unsigned short* __restrict__ q_h, const unsigned short* __restrict__ k_h,
    const unsigned short* __restrict__ vT_h, const float* __restrict__ y,
    const unsigned short* __restrict__ wo_h, const unsigned short* __restrict__ wo_l,
    float* __restrict__ out)
{
    __shared__ float sc_sh[16 * 648];   // 41472 B
    __shared__ float ctx_sh[64 * 17];   // 4352 B
    __shared__ float red_sh[256];
    __shared__ float rden[16];

    int b = blockIdx.y, t0 = blockIdx.x * 16, tid = threadIdx.x;
    int wave = tid >> 6, lane = tid & 63;
    int quad = lane >> 4, nlo = lane & 15;

    // ---- scores: wave w covers s in [w*160, (w+1)*160) ----
    // A-frag (q): m=t=nlo, k=c=quad*8+j (+32 for kstep 1). Pad rows are 0.
    const unsigned short* qb = q_h + ((size_t)b * TPAD + t0 + nlo) * 64 + quad * 8;
    bf16x8 qa0 = *(const bf16x8*)(qb);
    bf16x8 qa1 = *(const bf16x8*)(qb + 32);
    const unsigned short* kbase = k_h + (size_t)b * TPAD * 64 + quad * 8;
#pragma unroll 1
    for (int nt = 0; nt < 10; ++nt) {
        int s = (wave * 10 + nt) * 16 + nlo;          // B n-index
        const unsigned short* krow = kbase + (size_t)s * 64;
        bf16x8 kb0 = *(const bf16x8*)(krow);
        bf16x8 kb1 = *(const bf16x8*)(krow + 32);
        f32x4 acc = {0.f, 0.f, 0.f, 0.f};
        acc = mfma_bf16(qa0, kb0, acc);
        acc = mfma_bf16(qa1, kb1, acc);
#pragma unroll
        for (int r = 0; r < 4; ++r)
            sc_sh[(quad * 4 + r) * 648 + s] = acc[r] * 0.125f;
    }
    __syncthreads();

    // ---- softmax over s (2-pass; pad cols [625,640) hold 0 raw = P 0) ----
    int ti1 = tid >> 4, sg = tid & 15;
    float mx = -3.0e38f;
    for (int s = sg; s < TOUT; s += 16) mx = fmaxf(mx, sc_sh[ti1 * 648 + s]);
    red_sh[tid] = mx;
    __syncthreads();
    float rowm = red_sh[ti1 * 16];
#pragma unroll
    for (int l = 1; l < 16; l++) rowm = fmaxf(rowm, red_sh[ti1 * 16 + l]);
    __syncthreads();
    float sum = 0.f;
    for (int s = sg; s < TOUT; s += 16) {
        float e = __expf(sc_sh[ti1 * 648 + s] - rowm);
        sc_sh[ti1 * 648 + s] = e;
        sum += e;
    }
    red_sh[tid] = sum;
    __syncthreads();
    if (tid < 16) {
        float tot = 0.f;
#pragma unroll
        for (int l = 0; l < 16; l++) tot += red_sh[tid * 16 + l];
        rden[tid] = 1.f / tot;
    }
    __syncthreads();

    // ---- PV: wave w -> c-tile w (n = c = w*16+nlo). K = s, 20 steps of 32 ----
    const unsigned short* vb = vT_h + ((size_t)b * 64 + wave * 16 + nlo) * TPAD;
    f32x4 cacc = {0.f, 0.f, 0.f, 0.f};
#pragma unroll 1
    for (int ks = 0; ks < 20; ++ks) {
        const float* pr = &sc_sh[nlo * 648 + ks * 32 + quad * 8];
        union { unsigned short u[8]; bf16x8 v; } P;
#pragma unroll
        for (int j = 0; j < 8; ++j) P.u[j] = f32_to_bf16_rne(pr[j]);
        bf16x8 v8 = *(const bf16x8*)(vb + ks * 32 + quad * 8);
        cacc = mfma_bf16(P.v, v8, cacc);
    }
    // C: col=nlo=c-within-tile, row=quad*4+r = t; normalize, store ctx[c][t]
#pragma unroll
    for (int r = 0; r < 4; ++r)
        ctx_sh[(wave * 16 + nlo) * 17 + quad * 4 + r] = cacc[r] * rden[quad * 4 + r];
    __syncthreads();

    // ---- epilogue: out = y + wo @ ctx. Wave w -> o-tile w. ----
    const unsigned short* woh = wo_h + (size_t)(wave * 16 + nlo) * 64 + quad * 8;
    const unsigned short* wol = wo_l + (size_t)(wave * 16 + nlo) * 64 + quad * 8;
    f32x4 oacc = {0.f, 0.f, 0.f, 0.f};
#pragma unroll
    for (int ks = 0; ks < 2; ++ks) {
        union { unsigned short u[8]; bf16x8 v; } Bc;
#pragma unroll
        for (int j = 0; j < 8; ++j)
            Bc.u[j] = f32_to_bf16_rne(ctx_sh[(ks * 32 + quad * 8 + j) * 17 + nlo]);
        bf16x8 ah = *(const bf16x8*)(woh + ks * 32);
        bf16x8 al = *(const bf16x8*)(wol + ks * 32);
        oacc = mfma_bf16(ah, Bc.v, oacc);
        oacc = mfma_bf16(al, Bc.v, oacc);
    }
    int t_g = t0 + nlo;   // C col = nlo = t
    if (t_g < TOUT) {
#pragma unroll
        for (int r = 0; r < 4; ++r) {
            int o = wave * 16 + quad * 4 + r;
            size_t off = ((size_t)b * COUT + o) * TOUT + t_g;
            out[off] = y[off] + oacc[r];
        }
    }
}

// ---------------------------------------------------------------------------
extern "C" void kernel_launch(void* const* d_in, const int* in_sizes, int n_in,
                              void* d_out, int out_size, void* d_ws, size_t ws_size,
                              hipStream_t stream) {
    const float* x        = (const float*)d_in[0];
    const float* conv_w   = (const float*)d_in[1];
    const float* conv_b   = (const float*)d_in[2];
    const float* bn_gamma = (const float*)d_in[3];
    const float* bn_beta  = (const float*)d_in[4];
    const float* bn_mean  = (const float*)d_in[5];
    const float* bn_var   = (const float*)d_in[6];
    const float* wq       = (const float*)d_in[7];
    const float* wk       = (const float*)d_in[8];
    const float* wv       = (const float*)d_in[9];
    const float* wo       = (const float*)d_in[10];
    float* out = (float*)d_out;
    float* ws  = (float*)d_ws;

    // ws layout (float offsets)
    unsigned* sgn2        = (unsigned*)ws;                    // 6912 u32 -> [0, 8192)
    float* alpha          = ws + 8192;                        // 64
    float* scA            = ws + 8256;                        // 64
    float* scB            = ws + 8320;                        // 64
    float* wT4            = ws + 8448;                        // 3*4096 (wqT,wkT,wvT)
    unsigned short* wo_h  = (unsigned short*)(ws + 25088);    // 4096 ush = 2048 f
    unsigned short* wo_l  = (unsigned short*)(ws + 27136);    // 2048 f
    float* yb             = ws + 32768;                       // 5,120,000
    unsigned short* q_h   = (unsigned short*)(ws + 5152768);  // 128*640*64 ush = 2,621,440 f
    unsigned short* k_h   = (unsigned short*)(ws + 7774208);
    unsigned short* vT_h  = (unsigned short*)(ws + 10395648); // ends 13,017,088 f (~52 MB)

    hipLaunchKernelGGL(binarize_kernel, dim3(64), dim3(256), 0, stream, conv_w, sgn2, alpha);
    hipLaunchKernelGGL(transpose_w_kernel, dim3(5), dim3(256), 0, stream,
                       wq, wk, wv, wo, conv_b, bn_gamma, bn_beta, bn_mean, bn_var, alpha,
                       wT4, wo_h, wo_l, scA, scB);
    hipLaunchKernelGGL(conv_kernel, dim3(20, 128), dim3(256), 0, stream,
                       x, sgn2, scA, scB, yb);
    hipLaunchKernelGGL(proj_kernel, dim3(5, 128), dim3(256), 0, stream,
                       yb, wT4, wT4 + 4096, wT4 + 8192, q_h, k_h, vT_h);
    hipLaunchKernelGGL(attn_kernel, dim3(40, 128), dim3(256), 0, stream,
                       q_h, k_h, vT_h, yb, wo_h, wo_l, out);
}